// Round 4
// baseline (308.688 us; speedup 1.0000x reference)
//
#include <hip/hip_runtime.h>

#define DIM 512
#define B_  64
#define L_  2048

typedef unsigned short u16;
typedef float f32x4 __attribute__((ext_vector_type(4)));
typedef short s16x8 __attribute__((ext_vector_type(8)));
typedef short s16x4 __attribute__((ext_vector_type(4)));

__device__ __forceinline__ u16 f2bf(float f) {
  union { float f; unsigned u; } x{f};
  unsigned r = x.u + 0x7FFFu + ((x.u >> 16) & 1u);
  return (u16)(r >> 16);
}

__device__ __forceinline__ float tanh_fast(float x) {
  float e2 = __expf(2.0f * x);
  return 1.0f - 2.0f / (e2 + 1.0f);
}

// 8 f32 -> 8 bf16 via v_cvt_pk_bf16_f32 (no builtin on gfx950; RNE)
__device__ __forceinline__ s16x8 cvt8(f32x4 a, f32x4 b) {
  union { s16x8 h; unsigned u[4]; } r;
  asm("v_cvt_pk_bf16_f32 %0, %1, %2" : "=v"(r.u[0]) : "v"(a.x), "v"(a.y));
  asm("v_cvt_pk_bf16_f32 %0, %1, %2" : "=v"(r.u[1]) : "v"(a.z), "v"(a.w));
  asm("v_cvt_pk_bf16_f32 %0, %1, %2" : "=v"(r.u[2]) : "v"(b.x), "v"(b.y));
  asm("v_cvt_pk_bf16_f32 %0, %1, %2" : "=v"(r.u[3]) : "v"(b.z), "v"(b.w));
  return r.h;
}

// ---------- prep: q = query @ Wq^T + bq ; Wr -> bf16 transposed [t][o][kk] ----------
__global__ __launch_bounds__(256) void prep_kernel(
    const float* __restrict__ query, const float* __restrict__ Wq,
    const float* __restrict__ bq, const float* __restrict__ Wr,
    float* __restrict__ q_out, u16* __restrict__ Wrbt) {
  const int blk = blockIdx.x;
  const int tid = threadIdx.x;
  if (blk < 64) {
    __shared__ float qs[DIM];
    for (int i = tid; i < DIM; i += 256) qs[i] = query[blk * DIM + i];
    __syncthreads();
    for (int o = tid; o < DIM; o += 256) {
      const float* w = Wq + o * DIM;
      float acc = 0.f;
      for (int k = 0; k < DIM; k += 4) {
        f32x4 a = *(const f32x4*)&qs[k];
        f32x4 b = *(const f32x4*)&w[k];
        acc += a.x * b.x + a.y * b.y + a.z * b.z + a.w * b.w;
      }
      q_out[blk * DIM + o] = acc + bq[o];
    }
  } else {
    const int c = blk - 64;
    const int flat = c * 4096 + tid * 16;          // 16 consecutive k within one o-row
    const int o = flat >> 9, k0 = flat & 511;
    const int t = k0 >> 5, kk = k0 & 31;           // 16 elems stay inside chunk t
    u16* dst = Wrbt + t * 16384 + o * 32 + kk;
#pragma unroll
    for (int i = 0; i < 4; ++i) {
      f32x4 a = *(const f32x4*)&Wr[flat + i * 4];
      s16x4 o4;
      o4.x = (short)f2bf(a.x); o4.y = (short)f2bf(a.y);
      o4.z = (short)f2bf(a.z); o4.w = (short)f2bf(a.w);
      *(s16x4*)&dst[i * 4] = o4;
    }
  }
}

// ---------- main: barrier-free streaming GEMM + fused epilogue ----------
// grid (16 l-tiles, 64 b); 512 thr = 8 waves (4 o-waves x 2 l-waves), 128o x 64l each.
// A (Wrbt bf16) global->reg, L2-hot. B (ref f32) global->reg, cvt_pk in-register,
// software-pipelined one k-chunk ahead. No LDS / no barriers in the loop.
__global__ __launch_bounds__(512, 2) void attn_main(
    const float* __restrict__ ref, const u16* __restrict__ Wrbt,
    const float* __restrict__ q, const float* __restrict__ br,
    const float* __restrict__ v, float* __restrict__ e_out,
    float* __restrict__ logits) {
  __shared__ float u_lds[4][128];

  const int lt = blockIdx.x, b = blockIdx.y;
  const int l0 = lt * 128;
  const int tid = threadIdx.x, lane = tid & 63, w = tid >> 6;
  const int ow = w >> 1, lw = w & 1;
  const int rr = lane & 15, kg = lane >> 4;

  // B-frag row pointers: row l = l0 + lw*64 + fn*16 + rr, col k = t*32 + kg*8
  const float* refp[4];
#pragma unroll
  for (int fn = 0; fn < 4; ++fn)
    refp[fn] = ref + (size_t)(l0 + lw * 64 + fn * 16 + rr) * (B_ * DIM)
             + (size_t)b * DIM + kg * 8;
  // A-frag base: Wrbt[t][o = ow*128 + fm*16 + rr][kg*8]
  const u16* ap = Wrbt + (ow * 128 + rr) * 32 + kg * 8;

  f32x4 rn[4][2];
#pragma unroll
  for (int fn = 0; fn < 4; ++fn) {
    rn[fn][0] = *(const f32x4*)(refp[fn]);
    rn[fn][1] = *(const f32x4*)(refp[fn] + 4);
  }

  f32x4 acc[8][4];
#pragma unroll
  for (int fm = 0; fm < 8; ++fm)
#pragma unroll
    for (int fn = 0; fn < 4; ++fn) acc[fm][fn] = (f32x4){0.f, 0.f, 0.f, 0.f};

  for (int t = 0; t < 16; ++t) {
    s16x8 af[8];
#pragma unroll
    for (int fm = 0; fm < 8; ++fm)
      af[fm] = *(const s16x8*)(ap + t * 16384 + fm * 512);
    s16x8 bf[4];
#pragma unroll
    for (int fn = 0; fn < 4; ++fn) bf[fn] = cvt8(rn[fn][0], rn[fn][1]);
    if (t < 15) {  // prefetch next k-chunk of ref (hides HBM latency under MFMA)
#pragma unroll
      for (int fn = 0; fn < 4; ++fn) {
        rn[fn][0] = *(const f32x4*)(refp[fn] + (t + 1) * 32);
        rn[fn][1] = *(const f32x4*)(refp[fn] + (t + 1) * 32 + 4);
      }
    }
#pragma unroll
    for (int fm = 0; fm < 8; ++fm)
#pragma unroll
      for (int fn = 0; fn < 4; ++fn)
        acc[fm][fn] = __builtin_amdgcn_mfma_f32_16x16x32_bf16(bf[fn], af[fm], acc[fm][fn], 0, 0, 0);
  }

  // epilogue: e = acc + br ; u = sum_o v * tanh(acc + q + br). acc rows = l.
  const int ob = ow * 128;
  f32x4 usA[4];
#pragma unroll
  for (int fn = 0; fn < 4; ++fn) usA[fn] = (f32x4){0.f, 0.f, 0.f, 0.f};
#pragma unroll
  for (int fm = 0; fm < 8; ++fm) {
    const int o = ob + fm * 16 + rr;
    const float brv = br[o];
    const float qv = q[b * DIM + o] + brv;
    const float vv = v[o];
    const size_t erow = ((size_t)(b * DIM + o)) * L_;
#pragma unroll
    for (int fn = 0; fn < 4; ++fn) {
      const int lb = l0 + lw * 64 + fn * 16 + kg * 4;
      f32x4 a = acc[fm][fn];
      f32x4 ev = a + brv;
      __builtin_nontemporal_store(ev, (f32x4*)&e_out[erow + lb]);
      f32x4 th;
      th.x = tanh_fast(a.x + qv);
      th.y = tanh_fast(a.y + qv);
      th.z = tanh_fast(a.z + qv);
      th.w = tanh_fast(a.w + qv);
      usA[fn] += vv * th;
    }
  }
#pragma unroll
  for (int fn = 0; fn < 4; ++fn) {
    f32x4 us = usA[fn];
#pragma unroll
    for (int msk = 1; msk <= 8; msk <<= 1) {
      us.x += __shfl_xor(us.x, msk);
      us.y += __shfl_xor(us.y, msk);
      us.z += __shfl_xor(us.z, msk);
      us.w += __shfl_xor(us.w, msk);
    }
    if (rr == 0)
      *(f32x4*)&u_lds[ow][lw * 64 + fn * 16 + kg * 4] = us;
  }
  __syncthreads();
  if (tid < 128)
    logits[(size_t)b * L_ + l0 + tid] =
        u_lds[0][tid] + u_lds[1][tid] + u_lds[2][tid] + u_lds[3][tid];
}

extern "C" void kernel_launch(void* const* d_in, const int* in_sizes, int n_in,
                              void* d_out, int out_size, void* d_ws, size_t ws_size,
                              hipStream_t stream) {
  const float* query = (const float*)d_in[0];
  const float* ref   = (const float*)d_in[1];
  const float* Wq    = (const float*)d_in[2];
  const float* bq    = (const float*)d_in[3];
  const float* Wr    = (const float*)d_in[4];
  const float* br    = (const float*)d_in[5];
  const float* v     = (const float*)d_in[6];

  float* e_out  = (float*)d_out;
  float* logits = e_out + (size_t)B_ * DIM * L_;  // 67108864

  char* ws = (char*)d_ws;
  u16*   Wrbt = (u16*)ws;               // 512 KB  [16][512][32] bf16
  float* q    = (float*)(ws + 524288);  // 128 KB

  prep_kernel<<<128, 256, 0, stream>>>(query, Wq, bq, Wr, q, Wrbt);
  attn_main<<<dim3(16, 64), 512, 0, stream>>>(ref, Wrbt, q, br, v, e_out, logits);
}